// Round 1
// baseline (369.897 us; speedup 1.0000x reference)
//
#include <hip/hip_runtime.h>

#define NSP 200000
#define NE  1200000
#define DIM 128
#define NTILE 12500        // NSP/16
#define NBSCAN 196         // ceil(NSP/1024)

typedef __attribute__((ext_vector_type(8))) short short8;
typedef __attribute__((ext_vector_type(4))) short short4v;
typedef __attribute__((ext_vector_type(4))) float f32x4;

// ---- workspace byte offsets (all 16B aligned) ----
#define OFF_ROWPTR 0              // (NSP+1)*4 = 800004
#define OFF_CNT    800016        // NSP*4
#define OFF_CURSOR 1600016       // NSP*4   (contiguous with CNT for one memset)
#define OFF_BSUM   2400016       // 196*4
#define OFF_BOFF   2401040       // 196*4
#define OFF_CSR    2402064       // NE*4
#define OFF_WT     7202064       // 3*128*128*2 bf16 (W1^T, W2^T, Wp^T)

__device__ __forceinline__ unsigned short f2bf(float x){
  union { float f; unsigned u; } v; v.f = x;
  unsigned r = v.u + 0x7FFFu + ((v.u >> 16) & 1u);   // RNE
  return (unsigned short)(r >> 16);
}
__device__ __forceinline__ float lrelu(float x){ return x > 0.f ? x : 0.2f * x; }

// swizzled byte offset inside a [rows][128] bf16 LDS tile (row stride 256B)
// XOR bit-4 with row&7 -> spreads the stride-256B column access over 8 16B slots
__device__ __forceinline__ int lbyte(int row, int kb){
  return row * 256 + (kb ^ ((row & 7) << 4));
}

// ---- transpose W's to bf16 W^T in ws (once per launch) ----
__global__ void k_wt(const float* __restrict__ W1, const float* __restrict__ W2,
                     const float* __restrict__ Wp, unsigned short* __restrict__ wt){
  int i = blockIdx.x * 256 + threadIdx.x;          // 0..49151
  int m = i >> 14, e = i & 16383;
  int k = e >> 7, c = e & 127;
  const float* W = (m == 0) ? W1 : (m == 1) ? W2 : Wp;
  wt[m * 16384 + c * 128 + k] = f2bf(W[e]);        // Wt[c][k] = W[k][c]
}

// ---- degree histogram ----
__global__ void k_deg(const int* __restrict__ row, unsigned* __restrict__ cnt){
  int i = blockIdx.x * 256 + threadIdx.x;
  if (i < NE) atomicAdd(&cnt[row[i]], 1u);
}

// ---- scan step 1: per-1024-chunk sums ----
__global__ void k_bsum(const unsigned* __restrict__ cnt, unsigned* __restrict__ bsum){
  __shared__ unsigned sm[256];
  int base = blockIdx.x * 1024;
  unsigned s = 0;
  #pragma unroll
  for (int j = 0; j < 4; ++j){
    int idx = base + threadIdx.x * 4 + j;
    if (idx < NSP) s += cnt[idx];
  }
  sm[threadIdx.x] = s; __syncthreads();
  for (int off = 128; off > 0; off >>= 1){
    if (threadIdx.x < (unsigned)off) sm[threadIdx.x] += sm[threadIdx.x + off];
    __syncthreads();
  }
  if (threadIdx.x == 0) bsum[blockIdx.x] = sm[0];
}

// ---- scan step 2: exclusive scan of chunk sums (single block) ----
__global__ void k_boff(const unsigned* __restrict__ bsum, unsigned* __restrict__ boff,
                       unsigned* __restrict__ rowptr){
  __shared__ unsigned sm[256];
  unsigned v = (threadIdx.x < NBSCAN) ? bsum[threadIdx.x] : 0u;
  sm[threadIdx.x] = v; __syncthreads();
  for (int off = 1; off < 256; off <<= 1){
    unsigned t = (threadIdx.x >= (unsigned)off) ? sm[threadIdx.x - off] : 0u;
    __syncthreads();
    sm[threadIdx.x] += t;
    __syncthreads();
  }
  if (threadIdx.x < NBSCAN) boff[threadIdx.x] = sm[threadIdx.x] - v;  // exclusive
  if (threadIdx.x == 255) rowptr[NSP] = sm[255];                      // total = NE
}

// ---- scan step 3: per-chunk exclusive scan + chunk offset -> rowptr ----
__global__ void k_scan(const unsigned* __restrict__ cnt, const unsigned* __restrict__ boff,
                       unsigned* __restrict__ rowptr){
  __shared__ unsigned wsum[4];
  int base = blockIdx.x * 1024;
  int t = threadIdx.x, lane = t & 63, w = t >> 6;
  unsigned c[4], s = 0;
  #pragma unroll
  for (int j = 0; j < 4; ++j){
    int idx = base + t * 4 + j;
    c[j] = (idx < NSP) ? cnt[idx] : 0u;
    s += c[j];
  }
  unsigned inc = s;
  #pragma unroll
  for (int off = 1; off < 64; off <<= 1){
    unsigned n = __shfl_up(inc, (unsigned)off, 64);
    if (lane >= off) inc += n;
  }
  if (lane == 63) wsum[w] = inc;
  __syncthreads();
  unsigned woff = 0;
  for (int i = 0; i < w; ++i) woff += wsum[i];
  unsigned excl = boff[blockIdx.x] + woff + (inc - s);
  #pragma unroll
  for (int j = 0; j < 4; ++j){
    int idx = base + t * 4 + j;
    if (idx < NSP) rowptr[idx] = excl;
    excl += c[j];
  }
}

// ---- fill CSR col list ----
__global__ void k_fill(const int* __restrict__ row, const int* __restrict__ col,
                       const unsigned* __restrict__ rowptr, unsigned* __restrict__ cursor,
                       int* __restrict__ csr){
  int i = blockIdx.x * 256 + threadIdx.x;
  if (i < NE){
    int r = row[i];
    unsigned p = rowptr[r] + atomicAdd(&cursor[r], 1u);
    csr[p] = col[i];
  }
}

// ---- agg[s] = sum_{e in row s} u[csr[e]]  (unnormalized), one wave per spot ----
__global__ void k_agg(const float* __restrict__ u, const unsigned* __restrict__ rowptr,
                      const int* __restrict__ csr, float* __restrict__ agg){
  int wid = (blockIdx.x * 256 + threadIdx.x) >> 6;
  int lane = threadIdx.x & 63;
  if (wid >= NSP) return;
  unsigned e0 = rowptr[wid], e1 = rowptr[wid + 1];
  float a0 = 0.f, a1 = 0.f;
  for (unsigned e = e0; e < e1; ++e){
    int c = csr[e];
    float2 v = *(const float2*)(u + (size_t)c * DIM + lane * 2);
    a0 += v.x; a1 += v.y;
  }
  float2 o; o.x = a0; o.y = a1;
  *(float2*)(agg + (size_t)wid * DIM + lane * 2) = o;
}

// ---- fused: out = (leaky(u@W1+b1)@W2 + b2) + leaky((agg/deg)@Wp + bp) ----
// Computes transposed tiles D^T = W^T @ x^T per 16-spot tile.
// A-frag: W^T[i][k], i = ft*16 + (lane&15), k = ks*32 + (lane>>4)*8 + j (contig)
// B-frag: x[spot][k], spot = lane&15, same k  -> contiguous loads from spot rows
// D: col(lane&15)=spot, row=(lane>>4)*4+reg = feature (verified m89 layout)
__launch_bounds__(512)
__global__ void k_final(const float* __restrict__ u,
                        const float* __restrict__ b1,
                        const float* __restrict__ b2,
                        const float* __restrict__ bp,
                        const unsigned* __restrict__ rowptr,
                        const unsigned short* __restrict__ wt,
                        float* outagg){
  __shared__ __align__(16) char smem[131072];   // 3x32KB W^T + 8x4KB h

  // stage all three W^T into LDS (bf16, XOR-swizzled rows)
  for (int c = threadIdx.x; c < 6144; c += 512){
    int m = c >> 11, cc = c & 2047;
    int i = cc >> 4, kb = (cc & 15) << 4;
    short8 v = *(const short8*)(wt + m * 16384 + i * 128 + (kb >> 1));
    *(short8*)(smem + m * 32768 + lbyte(i, kb)) = v;
  }
  __syncthreads();

  const int wid = threadIdx.x >> 6, lane = threadIdx.x & 63;
  const int l15 = lane & 15, kg = lane >> 4;
  char* hbuf = smem + 98304 + wid * 4096;       // per-wave h tile [16][128] bf16

  for (int t = 0; t < 2; ++t){
    int tile = blockIdx.x * 16 + wid * 2 + t;
    if (tile >= NTILE) break;
    int s = tile * 16 + l15;
    const size_t srow = (size_t)s * DIM;

    f32x4 acc[8], hh[8];
    #pragma unroll
    for (int ft = 0; ft < 8; ++ft){ acc[ft] = (f32x4){0.f,0.f,0.f,0.f}; hh[ft] = (f32x4){0.f,0.f,0.f,0.f}; }

    // ---- stage C: acc = Wp^T @ agg^T ----
    #pragma unroll
    for (int ks = 0; ks < 4; ++ks){
      const float* p = outagg + srow + ks * 32 + kg * 8;
      float4 x0 = *(const float4*)p;
      float4 x1 = *(const float4*)(p + 4);
      short8 bf;
      bf[0]=(short)f2bf(x0.x); bf[1]=(short)f2bf(x0.y); bf[2]=(short)f2bf(x0.z); bf[3]=(short)f2bf(x0.w);
      bf[4]=(short)f2bf(x1.x); bf[5]=(short)f2bf(x1.y); bf[6]=(short)f2bf(x1.z); bf[7]=(short)f2bf(x1.w);
      #pragma unroll
      for (int ft = 0; ft < 8; ++ft){
        short8 af = *(const short8*)(smem + 2 * 32768 + lbyte(ft * 16 + l15, ks * 64 + kg * 16));
        acc[ft] = __builtin_amdgcn_mfma_f32_16x16x32_bf16(af, bf, acc[ft], 0, 0, 0);
      }
    }
    // normalize by degree, +bp, leaky
    {
      unsigned r0 = rowptr[s], r1 = rowptr[s + 1];
      float scl = (r1 > r0) ? 1.f / (float)(r1 - r0) : 0.f;
      #pragma unroll
      for (int ft = 0; ft < 8; ++ft){
        int f0 = ft * 16 + kg * 4;
        float4 bv = *(const float4*)(bp + f0);
        acc[ft][0] = lrelu(acc[ft][0] * scl + bv.x);
        acc[ft][1] = lrelu(acc[ft][1] * scl + bv.y);
        acc[ft][2] = lrelu(acc[ft][2] * scl + bv.z);
        acc[ft][3] = lrelu(acc[ft][3] * scl + bv.w);
      }
    }

    // ---- stage A: hh = W1^T @ u^T ----
    #pragma unroll
    for (int ks = 0; ks < 4; ++ks){
      const float* p = u + srow + ks * 32 + kg * 8;
      float4 x0 = *(const float4*)p;
      float4 x1 = *(const float4*)(p + 4);
      short8 bf;
      bf[0]=(short)f2bf(x0.x); bf[1]=(short)f2bf(x0.y); bf[2]=(short)f2bf(x0.z); bf[3]=(short)f2bf(x0.w);
      bf[4]=(short)f2bf(x1.x); bf[5]=(short)f2bf(x1.y); bf[6]=(short)f2bf(x1.z); bf[7]=(short)f2bf(x1.w);
      #pragma unroll
      for (int ft = 0; ft < 8; ++ft){
        short8 af = *(const short8*)(smem + 0 * 32768 + lbyte(ft * 16 + l15, ks * 64 + kg * 16));
        hh[ft] = __builtin_amdgcn_mfma_f32_16x16x32_bf16(af, bf, hh[ft], 0, 0, 0);
      }
    }
    // h = leaky(hh + b1) -> per-wave LDS tile h[spot][feature] (bf16, swizzled)
    #pragma unroll
    for (int ft = 0; ft < 8; ++ft){
      int f0 = ft * 16 + kg * 4;
      float4 bv = *(const float4*)(b1 + f0);
      short4v hv;
      hv[0] = (short)f2bf(lrelu(hh[ft][0] + bv.x));
      hv[1] = (short)f2bf(lrelu(hh[ft][1] + bv.y));
      hv[2] = (short)f2bf(lrelu(hh[ft][2] + bv.z));
      hv[3] = (short)f2bf(lrelu(hh[ft][3] + bv.w));
      *(short4v*)(hbuf + lbyte(l15, 2 * f0)) = hv;
    }

    // ---- stage B: acc += W2^T @ h^T ----
    #pragma unroll
    for (int ks = 0; ks < 4; ++ks){
      short8 bf = *(const short8*)(hbuf + lbyte(l15, ks * 64 + kg * 16));
      #pragma unroll
      for (int ft = 0; ft < 8; ++ft){
        short8 af = *(const short8*)(smem + 1 * 32768 + lbyte(ft * 16 + l15, ks * 64 + kg * 16));
        acc[ft] = __builtin_amdgcn_mfma_f32_16x16x32_bf16(af, bf, acc[ft], 0, 0, 0);
      }
    }

    // ---- epilogue: + b2, store out[spot][f] ----
    #pragma unroll
    for (int ft = 0; ft < 8; ++ft){
      int f0 = ft * 16 + kg * 4;
      float4 bv = *(const float4*)(b2 + f0);
      f32x4 o = acc[ft];
      o[0] += bv.x; o[1] += bv.y; o[2] += bv.z; o[3] += bv.w;
      *(f32x4*)(outagg + srow + f0) = o;
    }
  }
}

extern "C" void kernel_launch(void* const* d_in, const int* in_sizes, int n_in,
                              void* d_out, int out_size, void* d_ws, size_t ws_size,
                              hipStream_t stream){
  (void)in_sizes; (void)n_in; (void)out_size; (void)ws_size;
  const float* u  = (const float*)d_in[0];
  const float* W1 = (const float*)d_in[1];
  const float* b1 = (const float*)d_in[2];
  const float* W2 = (const float*)d_in[3];
  const float* b2 = (const float*)d_in[4];
  const float* Wp = (const float*)d_in[5];
  const float* bp = (const float*)d_in[6];
  const int* row  = (const int*)d_in[7];
  const int* col  = (const int*)d_in[8];
  char* ws = (char*)d_ws;
  unsigned* rowptr = (unsigned*)(ws + OFF_ROWPTR);
  unsigned* cnt    = (unsigned*)(ws + OFF_CNT);
  unsigned* cursor = (unsigned*)(ws + OFF_CURSOR);
  unsigned* bsum   = (unsigned*)(ws + OFF_BSUM);
  unsigned* boff   = (unsigned*)(ws + OFF_BOFF);
  int* csr         = (int*)(ws + OFF_CSR);
  unsigned short* wt = (unsigned short*)(ws + OFF_WT);
  float* out = (float*)d_out;

  hipMemsetAsync(ws + OFF_CNT, 0, 1600000, stream);     // cnt + cursor
  k_wt  <<<192, 256, 0, stream>>>(W1, W2, Wp, wt);
  k_deg <<<(NE + 255) / 256, 256, 0, stream>>>(row, cnt);
  k_bsum<<<NBSCAN, 256, 0, stream>>>(cnt, bsum);
  k_boff<<<1, 256, 0, stream>>>(bsum, boff, rowptr);
  k_scan<<<NBSCAN, 256, 0, stream>>>(cnt, boff, rowptr);
  k_fill<<<(NE + 255) / 256, 256, 0, stream>>>(row, col, rowptr, cursor, csr);
  k_agg <<<50000, 256, 0, stream>>>(u, rowptr, csr, out);
  k_final<<<782, 512, 0, stream>>>(u, b1, b2, bp, rowptr, wt, out);
}

// Round 2
// 300.720 us; speedup vs baseline: 1.2300x; 1.2300x over previous
//
#include <hip/hip_runtime.h>

#define NSP 200000
#define NE  1200000
#define DIM 128
#define NTILE 12500        // NSP/16
#define NBSCAN 196         // ceil(NSP/1024)

typedef __attribute__((ext_vector_type(8))) short short8;
typedef __attribute__((ext_vector_type(4))) short short4v;
typedef __attribute__((ext_vector_type(4))) float f32x4;

// ---- workspace byte offsets (all 16B aligned) ----
#define OFF_ROWPTR 0               // (NSP+1)*4
#define OFF_CNT    800016          // NSP*4
#define OFF_CURSOR 1600016         // NSP*4   (contiguous with CNT for one memset)
#define OFF_BSUM   2400016         // 196*4
#define OFF_BOFF   2401040         // 196*4
#define OFF_CSR    2402064         // NE*4
#define OFF_WT     7202064         // 3*128*128*2 bf16
#define OFF_UB     7300368         // NSP*128*2 bf16 u
#define OFF_AGGB   58500368        // NSP*128*2 bf16 agg (unnormalized)
#define WS_NEEDED  109700368ULL

__device__ __forceinline__ unsigned short f2bf(float x){
  union { float f; unsigned u; } v; v.f = x;
  unsigned r = v.u + 0x7FFFu + ((v.u >> 16) & 1u);   // RNE
  return (unsigned short)(r >> 16);
}
__device__ __forceinline__ float bflo(unsigned v){ union{unsigned u;float f;}x; x.u = v << 16; return x.f; }
__device__ __forceinline__ float bfhi(unsigned v){ union{unsigned u;float f;}x; x.u = v & 0xffff0000u; return x.f; }
__device__ __forceinline__ float lrelu(float x){ return x > 0.f ? x : 0.2f * x; }

// swizzled byte offset inside a [rows][128] bf16 LDS tile (row stride 256B)
__device__ __forceinline__ int lbyte(int row, int kb){
  return row * 256 + (kb ^ ((row & 7) << 4));
}

// ---- u (f32) -> ub (bf16), 8 elems/thread ----
__global__ void k_cast(const float* __restrict__ u, unsigned short* __restrict__ ub){
  size_t i = (size_t)blockIdx.x * 256 + threadIdx.x;     // 3.2M threads
  const float4* p = (const float4*)(u + i * 8);
  float4 x0 = p[0], x1 = p[1];
  short8 v;
  v[0]=(short)f2bf(x0.x); v[1]=(short)f2bf(x0.y); v[2]=(short)f2bf(x0.z); v[3]=(short)f2bf(x0.w);
  v[4]=(short)f2bf(x1.x); v[5]=(short)f2bf(x1.y); v[6]=(short)f2bf(x1.z); v[7]=(short)f2bf(x1.w);
  *(short8*)(ub + i * 8) = v;
}

// ---- transpose W's to bf16 W^T in ws ----
__global__ void k_wt(const float* __restrict__ W1, const float* __restrict__ W2,
                     const float* __restrict__ Wp, unsigned short* __restrict__ wt){
  int i = blockIdx.x * 256 + threadIdx.x;
  int m = i >> 14, e = i & 16383;
  int k = e >> 7, c = e & 127;
  const float* W = (m == 0) ? W1 : (m == 1) ? W2 : Wp;
  wt[m * 16384 + c * 128 + k] = f2bf(W[e]);
}

// ---- degree histogram ----
__global__ void k_deg(const int* __restrict__ row, unsigned* __restrict__ cnt){
  int i = blockIdx.x * 256 + threadIdx.x;
  if (i < NE) atomicAdd(&cnt[row[i]], 1u);
}

__global__ void k_bsum(const unsigned* __restrict__ cnt, unsigned* __restrict__ bsum){
  __shared__ unsigned sm[256];
  int base = blockIdx.x * 1024;
  unsigned s = 0;
  #pragma unroll
  for (int j = 0; j < 4; ++j){
    int idx = base + threadIdx.x * 4 + j;
    if (idx < NSP) s += cnt[idx];
  }
  sm[threadIdx.x] = s; __syncthreads();
  for (int off = 128; off > 0; off >>= 1){
    if (threadIdx.x < (unsigned)off) sm[threadIdx.x] += sm[threadIdx.x + off];
    __syncthreads();
  }
  if (threadIdx.x == 0) bsum[blockIdx.x] = sm[0];
}

__global__ void k_boff(const unsigned* __restrict__ bsum, unsigned* __restrict__ boff,
                       unsigned* __restrict__ rowptr){
  __shared__ unsigned sm[256];
  unsigned v = (threadIdx.x < NBSCAN) ? bsum[threadIdx.x] : 0u;
  sm[threadIdx.x] = v; __syncthreads();
  for (int off = 1; off < 256; off <<= 1){
    unsigned t = (threadIdx.x >= (unsigned)off) ? sm[threadIdx.x - off] : 0u;
    __syncthreads();
    sm[threadIdx.x] += t;
    __syncthreads();
  }
  if (threadIdx.x < NBSCAN) boff[threadIdx.x] = sm[threadIdx.x] - v;
  if (threadIdx.x == 255) rowptr[NSP] = sm[255];
}

__global__ void k_scan(const unsigned* __restrict__ cnt, const unsigned* __restrict__ boff,
                       unsigned* __restrict__ rowptr){
  __shared__ unsigned wsum[4];
  int base = blockIdx.x * 1024;
  int t = threadIdx.x, lane = t & 63, w = t >> 6;
  unsigned c[4], s = 0;
  #pragma unroll
  for (int j = 0; j < 4; ++j){
    int idx = base + t * 4 + j;
    c[j] = (idx < NSP) ? cnt[idx] : 0u;
    s += c[j];
  }
  unsigned inc = s;
  #pragma unroll
  for (int off = 1; off < 64; off <<= 1){
    unsigned n = __shfl_up(inc, (unsigned)off, 64);
    if (lane >= off) inc += n;
  }
  if (lane == 63) wsum[w] = inc;
  __syncthreads();
  unsigned woff = 0;
  for (int i = 0; i < w; ++i) woff += wsum[i];
  unsigned excl = boff[blockIdx.x] + woff + (inc - s);
  #pragma unroll
  for (int j = 0; j < 4; ++j){
    int idx = base + t * 4 + j;
    if (idx < NSP) rowptr[idx] = excl;
    excl += c[j];
  }
}

__global__ void k_fill(const int* __restrict__ row, const int* __restrict__ col,
                       const unsigned* __restrict__ rowptr, unsigned* __restrict__ cursor,
                       int* __restrict__ csr){
  int i = blockIdx.x * 256 + threadIdx.x;
  if (i < NE){
    int r = row[i];
    unsigned p = rowptr[r] + atomicAdd(&cursor[r], 1u);
    csr[p] = col[i];
  }
}

// ---- agg[s] = sum_{e in row s} u[csr[e]]  (unnormalized), one wave per spot.
// Lane-parallel index prefetch + shfl broadcast + 4x unroll -> independent gathers.
template<int BF>
__global__ void k_agg(const float* __restrict__ u, const unsigned short* __restrict__ ub,
                      const unsigned* __restrict__ rowptr, const int* __restrict__ csr,
                      float* __restrict__ aggf, unsigned short* __restrict__ aggb){
  int wid = (blockIdx.x * 256 + threadIdx.x) >> 6;
  int lane = threadIdx.x & 63;
  if (wid >= NSP) return;
  unsigned e0 = rowptr[wid], e1 = rowptr[wid + 1];
  int deg = (int)(e1 - e0);
  float a0 = 0.f, a1 = 0.f;
  for (int base = 0; base < deg; base += 64){
    int n = deg - base; if (n > 64) n = 64;
    int myidx = (lane < n) ? csr[e0 + base + lane] : 0;
    int j = 0;
    for (; j + 4 <= n; j += 4){
      int c0 = __shfl(myidx, j),     c1 = __shfl(myidx, j + 1);
      int c2 = __shfl(myidx, j + 2), c3 = __shfl(myidx, j + 3);
      if (BF){
        unsigned v0 = *(const unsigned*)(ub + (size_t)c0 * DIM + lane * 2);
        unsigned v1 = *(const unsigned*)(ub + (size_t)c1 * DIM + lane * 2);
        unsigned v2 = *(const unsigned*)(ub + (size_t)c2 * DIM + lane * 2);
        unsigned v3 = *(const unsigned*)(ub + (size_t)c3 * DIM + lane * 2);
        a0 += bflo(v0) + bflo(v1) + bflo(v2) + bflo(v3);
        a1 += bfhi(v0) + bfhi(v1) + bfhi(v2) + bfhi(v3);
      } else {
        float2 v0 = *(const float2*)(u + (size_t)c0 * DIM + lane * 2);
        float2 v1 = *(const float2*)(u + (size_t)c1 * DIM + lane * 2);
        float2 v2 = *(const float2*)(u + (size_t)c2 * DIM + lane * 2);
        float2 v3 = *(const float2*)(u + (size_t)c3 * DIM + lane * 2);
        a0 += v0.x + v1.x + v2.x + v3.x;
        a1 += v0.y + v1.y + v2.y + v3.y;
      }
    }
    for (; j < n; ++j){
      int c = __shfl(myidx, j);
      if (BF){
        unsigned v = *(const unsigned*)(ub + (size_t)c * DIM + lane * 2);
        a0 += bflo(v); a1 += bfhi(v);
      } else {
        float2 v = *(const float2*)(u + (size_t)c * DIM + lane * 2);
        a0 += v.x; a1 += v.y;
      }
    }
  }
  if (BF){
    unsigned o = (unsigned)f2bf(a0) | ((unsigned)f2bf(a1) << 16);
    *(unsigned*)(aggb + (size_t)wid * DIM + lane * 2) = o;
  } else {
    float2 o; o.x = a0; o.y = a1;
    *(float2*)(aggf + (size_t)wid * DIM + lane * 2) = o;
  }
}

// ---- fused: out = (leaky(u@W1+b1)@W2 + b2) + leaky((agg/deg)@Wp + bp) ----
template<int BF>
__launch_bounds__(512)
__global__ void k_final(const float* __restrict__ u, const unsigned short* __restrict__ ub,
                        const float* __restrict__ b1,
                        const float* __restrict__ b2,
                        const float* __restrict__ bp,
                        const unsigned* __restrict__ rowptr,
                        const unsigned short* __restrict__ wt,
                        const unsigned short* __restrict__ aggb,
                        float* outagg){
  __shared__ __align__(16) char smem[131072];   // 3x32KB W^T + 8x4KB h

  for (int c = threadIdx.x; c < 6144; c += 512){
    int m = c >> 11, cc = c & 2047;
    int i = cc >> 4, kb = (cc & 15) << 4;
    short8 v = *(const short8*)(wt + m * 16384 + i * 128 + (kb >> 1));
    *(short8*)(smem + m * 32768 + lbyte(i, kb)) = v;
  }
  __syncthreads();

  const int wid = threadIdx.x >> 6, lane = threadIdx.x & 63;
  const int l15 = lane & 15, kg = lane >> 4;
  char* hbuf = smem + 98304 + wid * 4096;

  for (int t = 0; t < 2; ++t){
    int tile = blockIdx.x * 16 + wid * 2 + t;
    if (tile >= NTILE) break;
    int s = tile * 16 + l15;
    const size_t srow = (size_t)s * DIM;

    f32x4 acc[8], hh[8];
    #pragma unroll
    for (int ft = 0; ft < 8; ++ft){ acc[ft] = (f32x4){0.f,0.f,0.f,0.f}; hh[ft] = (f32x4){0.f,0.f,0.f,0.f}; }

    // ---- stage C: acc = Wp^T @ agg^T ----
    #pragma unroll
    for (int ks = 0; ks < 4; ++ks){
      short8 bf;
      if (BF){
        bf = *(const short8*)(aggb + srow + ks * 32 + kg * 8);
      } else {
        const float* p = outagg + srow + ks * 32 + kg * 8;
        float4 x0 = *(const float4*)p;
        float4 x1 = *(const float4*)(p + 4);
        bf[0]=(short)f2bf(x0.x); bf[1]=(short)f2bf(x0.y); bf[2]=(short)f2bf(x0.z); bf[3]=(short)f2bf(x0.w);
        bf[4]=(short)f2bf(x1.x); bf[5]=(short)f2bf(x1.y); bf[6]=(short)f2bf(x1.z); bf[7]=(short)f2bf(x1.w);
      }
      #pragma unroll
      for (int ft = 0; ft < 8; ++ft){
        short8 af = *(const short8*)(smem + 2 * 32768 + lbyte(ft * 16 + l15, ks * 64 + kg * 16));
        acc[ft] = __builtin_amdgcn_mfma_f32_16x16x32_bf16(af, bf, acc[ft], 0, 0, 0);
      }
    }
    {
      unsigned r0 = rowptr[s], r1 = rowptr[s + 1];
      float scl = (r1 > r0) ? 1.f / (float)(r1 - r0) : 0.f;
      #pragma unroll
      for (int ft = 0; ft < 8; ++ft){
        int f0 = ft * 16 + kg * 4;
        float4 bv = *(const float4*)(bp + f0);
        acc[ft][0] = lrelu(acc[ft][0] * scl + bv.x);
        acc[ft][1] = lrelu(acc[ft][1] * scl + bv.y);
        acc[ft][2] = lrelu(acc[ft][2] * scl + bv.z);
        acc[ft][3] = lrelu(acc[ft][3] * scl + bv.w);
      }
    }

    // ---- stage A: hh = W1^T @ u^T ----
    #pragma unroll
    for (int ks = 0; ks < 4; ++ks){
      short8 bf;
      if (BF){
        bf = *(const short8*)(ub + srow + ks * 32 + kg * 8);
      } else {
        const float* p = u + srow + ks * 32 + kg * 8;
        float4 x0 = *(const float4*)p;
        float4 x1 = *(const float4*)(p + 4);
        bf[0]=(short)f2bf(x0.x); bf[1]=(short)f2bf(x0.y); bf[2]=(short)f2bf(x0.z); bf[3]=(short)f2bf(x0.w);
        bf[4]=(short)f2bf(x1.x); bf[5]=(short)f2bf(x1.y); bf[6]=(short)f2bf(x1.z); bf[7]=(short)f2bf(x1.w);
      }
      #pragma unroll
      for (int ft = 0; ft < 8; ++ft){
        short8 af = *(const short8*)(smem + 0 * 32768 + lbyte(ft * 16 + l15, ks * 64 + kg * 16));
        hh[ft] = __builtin_amdgcn_mfma_f32_16x16x32_bf16(af, bf, hh[ft], 0, 0, 0);
      }
    }
    #pragma unroll
    for (int ft = 0; ft < 8; ++ft){
      int f0 = ft * 16 + kg * 4;
      float4 bv = *(const float4*)(b1 + f0);
      short4v hv;
      hv[0] = (short)f2bf(lrelu(hh[ft][0] + bv.x));
      hv[1] = (short)f2bf(lrelu(hh[ft][1] + bv.y));
      hv[2] = (short)f2bf(lrelu(hh[ft][2] + bv.z));
      hv[3] = (short)f2bf(lrelu(hh[ft][3] + bv.w));
      *(short4v*)(hbuf + lbyte(l15, 2 * f0)) = hv;
    }

    // ---- stage B: acc += W2^T @ h^T ----
    #pragma unroll
    for (int ks = 0; ks < 4; ++ks){
      short8 bf = *(const short8*)(hbuf + lbyte(l15, ks * 64 + kg * 16));
      #pragma unroll
      for (int ft = 0; ft < 8; ++ft){
        short8 af = *(const short8*)(smem + 1 * 32768 + lbyte(ft * 16 + l15, ks * 64 + kg * 16));
        acc[ft] = __builtin_amdgcn_mfma_f32_16x16x32_bf16(af, bf, acc[ft], 0, 0, 0);
      }
    }

    // ---- epilogue ----
    #pragma unroll
    for (int ft = 0; ft < 8; ++ft){
      int f0 = ft * 16 + kg * 4;
      float4 bv = *(const float4*)(b2 + f0);
      f32x4 o = acc[ft];
      o[0] += bv.x; o[1] += bv.y; o[2] += bv.z; o[3] += bv.w;
      *(f32x4*)(outagg + srow + f0) = o;
    }
  }
}

extern "C" void kernel_launch(void* const* d_in, const int* in_sizes, int n_in,
                              void* d_out, int out_size, void* d_ws, size_t ws_size,
                              hipStream_t stream){
  (void)in_sizes; (void)n_in; (void)out_size;
  const float* u  = (const float*)d_in[0];
  const float* W1 = (const float*)d_in[1];
  const float* b1 = (const float*)d_in[2];
  const float* W2 = (const float*)d_in[3];
  const float* b2 = (const float*)d_in[4];
  const float* Wp = (const float*)d_in[5];
  const float* bp = (const float*)d_in[6];
  const int* row  = (const int*)d_in[7];
  const int* col  = (const int*)d_in[8];
  char* ws = (char*)d_ws;
  unsigned* rowptr = (unsigned*)(ws + OFF_ROWPTR);
  unsigned* cnt    = (unsigned*)(ws + OFF_CNT);
  unsigned* cursor = (unsigned*)(ws + OFF_CURSOR);
  unsigned* bsum   = (unsigned*)(ws + OFF_BSUM);
  unsigned* boff   = (unsigned*)(ws + OFF_BOFF);
  int* csr         = (int*)(ws + OFF_CSR);
  unsigned short* wt = (unsigned short*)(ws + OFF_WT);
  unsigned short* ubp   = (unsigned short*)(ws + OFF_UB);
  unsigned short* aggbp = (unsigned short*)(ws + OFF_AGGB);
  float* out = (float*)d_out;

  const bool bf = (ws_size >= WS_NEEDED);

  hipMemsetAsync(ws + OFF_CNT, 0, 1600000, stream);     // cnt + cursor
  k_wt  <<<192, 256, 0, stream>>>(W1, W2, Wp, wt);
  if (bf) k_cast<<<12500, 256, 0, stream>>>(u, ubp);
  k_deg <<<(NE + 255) / 256, 256, 0, stream>>>(row, cnt);
  k_bsum<<<NBSCAN, 256, 0, stream>>>(cnt, bsum);
  k_boff<<<1, 256, 0, stream>>>(bsum, boff, rowptr);
  k_scan<<<NBSCAN, 256, 0, stream>>>(cnt, boff, rowptr);
  k_fill<<<(NE + 255) / 256, 256, 0, stream>>>(row, col, rowptr, cursor, csr);
  if (bf){
    k_agg<1>  <<<50000, 256, 0, stream>>>(u, ubp, rowptr, csr, out, aggbp);
    k_final<1><<<782, 512, 0, stream>>>(u, ubp, b1, b2, bp, rowptr, wt, aggbp, out);
  } else {
    k_agg<0>  <<<50000, 256, 0, stream>>>(u, ubp, rowptr, csr, out, aggbp);
    k_final<0><<<782, 512, 0, stream>>>(u, ubp, b1, b2, bp, rowptr, wt, aggbp, out);
  }
}

// Round 3
// 235.913 us; speedup vs baseline: 1.5679x; 1.2747x over previous
//
#include <hip/hip_runtime.h>

#define NSP 200000
#define NE  1200000
#define DIM 128
#define NTILE 12500        // NSP/16
#define NBKT  782          // ceil(NSP/256) row-range buckets
#define MAXE  2560         // per-bucket edge capacity for LDS sort (mean 1536, sigma 39)

typedef __attribute__((ext_vector_type(8))) short short8;
typedef __attribute__((ext_vector_type(4))) short short4v;
typedef __attribute__((ext_vector_type(4))) float f32x4;

// ---- workspace byte offsets (16B aligned) ----
#define OFF_BB     0               // (NBKT+1)*4 bucket base (exclusive scan)
#define OFF_CUR    3136            // NBKT*4 bucket fill cursor
#define OFF_BCNT   6272            // NBKT*4 bucket counts
#define OFF_PAIRS  9408            // NE*4 packed (lr<<18)|col
#define OFF_WT     4809408         // 3*128*128*2 bf16 (W1^T,W2^T,Wp^T)
#define OFF_UB     4907712         // NSP*128*2 bf16 u
#define OFF_AGGB   56107712        // NSP*128*2 bf16 agg (normalized)
// WS_NEEDED = 107307712 (< 109.7MB confirmed available in round 2)

__device__ __forceinline__ unsigned short f2bf(float x){
  union { float f; unsigned u; } v; v.f = x;
  unsigned r = v.u + 0x7FFFu + ((v.u >> 16) & 1u);   // RNE
  return (unsigned short)(r >> 16);
}
__device__ __forceinline__ float bflo(unsigned v){ union{unsigned u;float f;}x; x.u = v << 16; return x.f; }
__device__ __forceinline__ float bfhi(unsigned v){ union{unsigned u;float f;}x; x.u = v & 0xffff0000u; return x.f; }
__device__ __forceinline__ float lrelu(float x){ return x > 0.f ? x : 0.2f * x; }

// swizzled byte offset inside a [rows][128] bf16 LDS tile (row stride 256B)
__device__ __forceinline__ int lbyte(int row, int kb){
  return row * 256 + (kb ^ ((row & 7) << 4));
}

// ---- u (f32) -> ub (bf16) ----
__global__ void k_cast(const float* __restrict__ u, unsigned short* __restrict__ ub){
  size_t i = (size_t)blockIdx.x * 256 + threadIdx.x;
  const float4* p = (const float4*)(u + i * 8);
  float4 x0 = p[0], x1 = p[1];
  short8 v;
  v[0]=(short)f2bf(x0.x); v[1]=(short)f2bf(x0.y); v[2]=(short)f2bf(x0.z); v[3]=(short)f2bf(x0.w);
  v[4]=(short)f2bf(x1.x); v[5]=(short)f2bf(x1.y); v[6]=(short)f2bf(x1.z); v[7]=(short)f2bf(x1.w);
  *(short8*)(ub + i * 8) = v;
}

// ---- transpose W's to bf16 W^T ----
__global__ void k_wt(const float* __restrict__ W1, const float* __restrict__ W2,
                     const float* __restrict__ Wp, unsigned short* __restrict__ wt){
  int i = blockIdx.x * 256 + threadIdx.x;
  int m = i >> 14, e = i & 16383;
  int k = e >> 7, c = e & 127;
  const float* W = (m == 0) ? W1 : (m == 1) ? W2 : Wp;
  wt[m * 16384 + c * 128 + k] = f2bf(W[e]);
}

// ---- bucket counts via per-block LDS histogram ----
__global__ void k_bcount(const int* __restrict__ row, unsigned* __restrict__ cnt){
  __shared__ unsigned hist[NBKT];
  for (int i = threadIdx.x; i < NBKT; i += 512) hist[i] = 0;
  __syncthreads();
  #pragma unroll
  for (int j = 0; j < 4; ++j){
    int i = blockIdx.x * 2048 + j * 512 + threadIdx.x;
    if (i < NE) atomicAdd(&hist[row[i] >> 8], 1u);
  }
  __syncthreads();
  for (int i = threadIdx.x; i < NBKT; i += 512){
    unsigned v = hist[i];
    if (v) atomicAdd(&cnt[i], v);
  }
}

// ---- exclusive scan of NBKT counts (1 block) -> bb, cur ----
__global__ void k_bscan(const unsigned* __restrict__ cnt, unsigned* __restrict__ bb,
                        unsigned* __restrict__ cur){
  __shared__ unsigned wsum[4];
  int t = threadIdx.x, lane = t & 63, w = t >> 6;
  unsigned c4[4], s = 0;
  #pragma unroll
  for (int j = 0; j < 4; ++j){
    int idx = t * 4 + j;
    c4[j] = (idx < NBKT) ? cnt[idx] : 0u;
    s += c4[j];
  }
  unsigned inc = s;
  #pragma unroll
  for (int off = 1; off < 64; off <<= 1){
    unsigned n = __shfl_up(inc, (unsigned)off, 64);
    if (lane >= off) inc += n;
  }
  if (lane == 63) wsum[w] = inc;
  __syncthreads();
  unsigned prior = 0;
  for (int i = 0; i < w; ++i) prior += wsum[i];
  unsigned excl = prior + (inc - s);
  #pragma unroll
  for (int j = 0; j < 4; ++j){
    int idx = t * 4 + j;
    if (idx < NBKT){
      bb[idx] = excl; cur[idx] = excl;
      excl += c4[j];
      if (idx == NBKT - 1) bb[NBKT] = excl;
    }
  }
}

// ---- bin edges into bucket regions (block-batched cursor grabs) ----
__global__ void k_bfill(const int* __restrict__ row, const int* __restrict__ col,
                        unsigned* __restrict__ cur, unsigned* __restrict__ pairs){
  __shared__ unsigned hist[NBKT], base[NBKT];
  for (int i = threadIdx.x; i < NBKT; i += 512) hist[i] = 0;
  __syncthreads();
  int r[16], c[16];
  #pragma unroll
  for (int j = 0; j < 16; ++j){
    int i = blockIdx.x * 8192 + j * 512 + threadIdx.x;
    r[j] = -1;
    if (i < NE){ r[j] = row[i]; c[j] = col[i]; atomicAdd(&hist[r[j] >> 8], 1u); }
  }
  __syncthreads();
  for (int i = threadIdx.x; i < NBKT; i += 512){
    unsigned n = hist[i];
    base[i] = n ? atomicAdd(&cur[i], n) : 0u;
    hist[i] = 0;
  }
  __syncthreads();
  #pragma unroll
  for (int j = 0; j < 16; ++j){
    if (r[j] >= 0){
      int b = r[j] >> 8;
      unsigned pos = base[b] + atomicAdd(&hist[b], 1u);
      pairs[pos] = ((unsigned)(r[j] & 255) << 18) | (unsigned)c[j];
    }
  }
}

// ---- per bucket: LDS counting-sort by local row, gather ub rows, write normalized agg ----
__launch_bounds__(256)
__global__ void k_bagg(const unsigned short* __restrict__ ub,
                       const unsigned* __restrict__ bb,
                       const unsigned* __restrict__ pairs,
                       unsigned short* __restrict__ aggb){
  __shared__ unsigned srt[MAXE];
  __shared__ unsigned hist[256], start[257], cur[256];
  __shared__ unsigned wsum[4];
  const int b = blockIdx.x, t = threadIdx.x;
  const int lane = t & 63, w = t >> 6;
  const unsigned base0 = bb[b], cnt = bb[b + 1] - base0;
  int nrows = NSP - b * 256; if (nrows > 256) nrows = 256;
  hist[t] = 0; cur[t] = 0;
  __syncthreads();

  if (cnt <= MAXE){
    for (unsigned i = t; i < cnt; i += 256) atomicAdd(&hist[pairs[base0 + i] >> 18], 1u);
    __syncthreads();
    // exclusive scan of hist[256]
    unsigned v = hist[t], inc = v;
    #pragma unroll
    for (int off = 1; off < 64; off <<= 1){
      unsigned n = __shfl_up(inc, (unsigned)off, 64);
      if (lane >= off) inc += n;
    }
    if (lane == 63) wsum[w] = inc;
    __syncthreads();
    unsigned prior = 0;
    for (int i = 0; i < w; ++i) prior += wsum[i];
    start[t] = prior + inc - v;
    if (t == 255) start[256] = prior + inc;
    __syncthreads();
    for (unsigned i = t; i < cnt; i += 256){
      unsigned p = pairs[base0 + i], lr = p >> 18;
      unsigned slot = start[lr] + atomicAdd(&cur[lr], 1u);
      srt[slot] = p & 0x3FFFFu;
    }
    __syncthreads();
    for (int r = w; r < nrows; r += 4){
      unsigned s0 = start[r], d = start[r + 1] - s0;
      float a0 = 0.f, a1 = 0.f;
      unsigned j = 0;
      for (; j + 4 <= d; j += 4){
        unsigned c0 = srt[s0 + j],     c1 = srt[s0 + j + 1];
        unsigned c2 = srt[s0 + j + 2], c3 = srt[s0 + j + 3];
        unsigned v0 = *(const unsigned*)(ub + (size_t)c0 * DIM + lane * 2);
        unsigned v1 = *(const unsigned*)(ub + (size_t)c1 * DIM + lane * 2);
        unsigned v2 = *(const unsigned*)(ub + (size_t)c2 * DIM + lane * 2);
        unsigned v3 = *(const unsigned*)(ub + (size_t)c3 * DIM + lane * 2);
        a0 += bflo(v0) + bflo(v1) + bflo(v2) + bflo(v3);
        a1 += bfhi(v0) + bfhi(v1) + bfhi(v2) + bfhi(v3);
      }
      for (; j < d; ++j){
        unsigned c = srt[s0 + j];
        unsigned vv = *(const unsigned*)(ub + (size_t)c * DIM + lane * 2);
        a0 += bflo(vv); a1 += bfhi(vv);
      }
      float scl = d ? 1.f / (float)d : 0.f;
      unsigned o = (unsigned)f2bf(a0 * scl) | ((unsigned)f2bf(a1 * scl) << 16);
      *(unsigned*)(aggb + (size_t)(b * 256 + r) * DIM + lane * 2) = o;
    }
  } else {
    // capacity overflow path (statistically unreachable): per-row scan of bucket
    for (int r = w; r < nrows; r += 4){
      float a0 = 0.f, a1 = 0.f; unsigned d = 0;
      for (unsigned i = 0; i < cnt; ++i){
        unsigned p = pairs[base0 + i];
        if ((int)(p >> 18) == r){
          unsigned c = p & 0x3FFFFu; ++d;
          unsigned vv = *(const unsigned*)(ub + (size_t)c * DIM + lane * 2);
          a0 += bflo(vv); a1 += bfhi(vv);
        }
      }
      float scl = d ? 1.f / (float)d : 0.f;
      unsigned o = (unsigned)f2bf(a0 * scl) | ((unsigned)f2bf(a1 * scl) << 16);
      *(unsigned*)(aggb + (size_t)(b * 256 + r) * DIM + lane * 2) = o;
    }
  }
}

// ---- fused: out = (leaky(u@W1+b1)@W2 + b2) + leaky(aggn@Wp + bp) ----
// D^T = W^T @ x^T per 16-spot tile; 16 waves/block, 1 tile/wave, 160KB LDS.
__launch_bounds__(1024)
__global__ void k_final(const unsigned short* __restrict__ ub,
                        const float* __restrict__ b1,
                        const float* __restrict__ b2,
                        const float* __restrict__ bp,
                        const unsigned short* __restrict__ wt,
                        const unsigned short* __restrict__ aggb,
                        float* __restrict__ out){
  __shared__ __align__(16) char smem[163840];   // 3x32KB W^T + 16x4KB h

  for (int c = threadIdx.x; c < 6144; c += 1024){
    int m = c >> 11, cc = c & 2047;
    int i = cc >> 4, kb = (cc & 15) << 4;
    short8 v = *(const short8*)(wt + m * 16384 + i * 128 + (kb >> 1));
    *(short8*)(smem + m * 32768 + lbyte(i, kb)) = v;
  }
  __syncthreads();

  const int wid = threadIdx.x >> 6, lane = threadIdx.x & 63;
  const int l15 = lane & 15, kg = lane >> 4;
  char* hbuf = smem + 98304 + wid * 4096;

  int tile = blockIdx.x * 16 + wid;
  if (tile >= NTILE) return;
  int s = tile * 16 + l15;
  const size_t srow = (size_t)s * DIM;

  f32x4 acc[8], hh[8];
  #pragma unroll
  for (int ft = 0; ft < 8; ++ft){ acc[ft] = (f32x4){0.f,0.f,0.f,0.f}; hh[ft] = (f32x4){0.f,0.f,0.f,0.f}; }

  // ---- stage C: acc = Wp^T @ aggn^T ----
  #pragma unroll
  for (int ks = 0; ks < 4; ++ks){
    short8 bf = *(const short8*)(aggb + srow + ks * 32 + kg * 8);
    #pragma unroll
    for (int ft = 0; ft < 8; ++ft){
      short8 af = *(const short8*)(smem + 2 * 32768 + lbyte(ft * 16 + l15, ks * 64 + kg * 16));
      acc[ft] = __builtin_amdgcn_mfma_f32_16x16x32_bf16(af, bf, acc[ft], 0, 0, 0);
    }
  }
  #pragma unroll
  for (int ft = 0; ft < 8; ++ft){
    int f0 = ft * 16 + kg * 4;
    float4 bv = *(const float4*)(bp + f0);
    acc[ft][0] = lrelu(acc[ft][0] + bv.x);
    acc[ft][1] = lrelu(acc[ft][1] + bv.y);
    acc[ft][2] = lrelu(acc[ft][2] + bv.z);
    acc[ft][3] = lrelu(acc[ft][3] + bv.w);
  }

  // ---- stage A: hh = W1^T @ u^T ----
  #pragma unroll
  for (int ks = 0; ks < 4; ++ks){
    short8 bf = *(const short8*)(ub + srow + ks * 32 + kg * 8);
    #pragma unroll
    for (int ft = 0; ft < 8; ++ft){
      short8 af = *(const short8*)(smem + 0 * 32768 + lbyte(ft * 16 + l15, ks * 64 + kg * 16));
      hh[ft] = __builtin_amdgcn_mfma_f32_16x16x32_bf16(af, bf, hh[ft], 0, 0, 0);
    }
  }
  #pragma unroll
  for (int ft = 0; ft < 8; ++ft){
    int f0 = ft * 16 + kg * 4;
    float4 bv = *(const float4*)(b1 + f0);
    short4v hv;
    hv[0] = (short)f2bf(lrelu(hh[ft][0] + bv.x));
    hv[1] = (short)f2bf(lrelu(hh[ft][1] + bv.y));
    hv[2] = (short)f2bf(lrelu(hh[ft][2] + bv.z));
    hv[3] = (short)f2bf(lrelu(hh[ft][3] + bv.w));
    *(short4v*)(hbuf + lbyte(l15, 2 * f0)) = hv;
  }

  // ---- stage B: acc += W2^T @ h^T ----
  #pragma unroll
  for (int ks = 0; ks < 4; ++ks){
    short8 bf = *(const short8*)(hbuf + lbyte(l15, ks * 64 + kg * 16));
    #pragma unroll
    for (int ft = 0; ft < 8; ++ft){
      short8 af = *(const short8*)(smem + 1 * 32768 + lbyte(ft * 16 + l15, ks * 64 + kg * 16));
      acc[ft] = __builtin_amdgcn_mfma_f32_16x16x32_bf16(af, bf, acc[ft], 0, 0, 0);
    }
  }

  // ---- epilogue ----
  #pragma unroll
  for (int ft = 0; ft < 8; ++ft){
    int f0 = ft * 16 + kg * 4;
    float4 bv = *(const float4*)(b2 + f0);
    f32x4 o = acc[ft];
    o[0] += bv.x; o[1] += bv.y; o[2] += bv.z; o[3] += bv.w;
    *(f32x4*)(out + srow + f0) = o;
  }
}

extern "C" void kernel_launch(void* const* d_in, const int* in_sizes, int n_in,
                              void* d_out, int out_size, void* d_ws, size_t ws_size,
                              hipStream_t stream){
  (void)in_sizes; (void)n_in; (void)out_size; (void)ws_size;
  const float* u  = (const float*)d_in[0];
  const float* W1 = (const float*)d_in[1];
  const float* b1 = (const float*)d_in[2];
  const float* W2 = (const float*)d_in[3];
  const float* b2 = (const float*)d_in[4];
  const float* Wp = (const float*)d_in[5];
  const float* bp = (const float*)d_in[6];
  const int* row  = (const int*)d_in[7];
  const int* col  = (const int*)d_in[8];
  char* ws = (char*)d_ws;
  unsigned* bb    = (unsigned*)(ws + OFF_BB);
  unsigned* cur   = (unsigned*)(ws + OFF_CUR);
  unsigned* bcnt  = (unsigned*)(ws + OFF_BCNT);
  unsigned* pairs = (unsigned*)(ws + OFF_PAIRS);
  unsigned short* wt    = (unsigned short*)(ws + OFF_WT);
  unsigned short* ubp   = (unsigned short*)(ws + OFF_UB);
  unsigned short* aggbp = (unsigned short*)(ws + OFF_AGGB);
  float* out = (float*)d_out;

  hipMemsetAsync(ws + OFF_BCNT, 0, 3136, stream);
  k_wt    <<<192, 256, 0, stream>>>(W1, W2, Wp, wt);
  k_cast  <<<12500, 256, 0, stream>>>(u, ubp);
  k_bcount<<<586, 512, 0, stream>>>(row, bcnt);
  k_bscan <<<1, 256, 0, stream>>>(bcnt, bb, cur);
  k_bfill <<<147, 512, 0, stream>>>(row, col, cur, pairs);
  k_bagg  <<<NBKT, 256, 0, stream>>>(ubp, bb, pairs, aggbp);
  k_final <<<782, 1024, 0, stream>>>(ubp, b1, b2, bp, wt, aggbp, out);
}

// Round 4
// 229.216 us; speedup vs baseline: 1.6137x; 1.0292x over previous
//
#include <hip/hip_runtime.h>

#define NSP 200000
#define NE  1200000
#define DIM 128
#define NTILE 12500        // NSP/16
#define NBKT  782          // ceil(NSP/256) row-range buckets
#define MAXE  2560         // per-bucket edge capacity for LDS sort (mean 1536, sigma 39)

typedef __attribute__((ext_vector_type(8))) short short8;
typedef __attribute__((ext_vector_type(4))) short short4v;
typedef __attribute__((ext_vector_type(4))) float f32x4;

// ---- workspace byte offsets (16B aligned), total 108.1MB (<109.7MB confirmed) ----
#define OFF_BB     0               // (NBKT+1)*4
#define OFF_CUR    3136            // NBKT*4
#define OFF_BCNT   6272            // NBKT*4
#define OFF_PAIRS  9408            // NE*4 packed (lr<<18)|col; sorted in place by k_sort
#define OFF_ROWPTR 4809408         // (NSP+1)*4
#define OFF_WT     5609424         // 3*128*128*2 bf16
#define OFF_UB     5707728         // NSP*128*2 bf16 u
#define OFF_AGGB   56907728        // NSP*128*2 bf16 agg (normalized)  end=108107728

__device__ __forceinline__ unsigned short f2bf(float x){
  union { float f; unsigned u; } v; v.f = x;
  unsigned r = v.u + 0x7FFFu + ((v.u >> 16) & 1u);   // RNE
  return (unsigned short)(r >> 16);
}
__device__ __forceinline__ float bflo(unsigned v){ union{unsigned u;float f;}x; x.u = v << 16; return x.f; }
__device__ __forceinline__ float bfhi(unsigned v){ union{unsigned u;float f;}x; x.u = v & 0xffff0000u; return x.f; }
__device__ __forceinline__ float lrelu(float x){ return x > 0.f ? x : 0.2f * x; }

// swizzled byte offset inside a [rows][128] bf16 LDS tile (row stride 256B)
__device__ __forceinline__ int lbyte(int row, int kb){
  return row * 256 + (kb ^ ((row & 7) << 4));
}

// ---- u (f32) -> ub (bf16) ----
__global__ void k_cast(const float* __restrict__ u, unsigned short* __restrict__ ub){
  size_t i = (size_t)blockIdx.x * 256 + threadIdx.x;
  const float4* p = (const float4*)(u + i * 8);
  float4 x0 = p[0], x1 = p[1];
  short8 v;
  v[0]=(short)f2bf(x0.x); v[1]=(short)f2bf(x0.y); v[2]=(short)f2bf(x0.z); v[3]=(short)f2bf(x0.w);
  v[4]=(short)f2bf(x1.x); v[5]=(short)f2bf(x1.y); v[6]=(short)f2bf(x1.z); v[7]=(short)f2bf(x1.w);
  *(short8*)(ub + i * 8) = v;
}

// ---- transpose W's to bf16 W^T ----
__global__ void k_wt(const float* __restrict__ W1, const float* __restrict__ W2,
                     const float* __restrict__ Wp, unsigned short* __restrict__ wt){
  int i = blockIdx.x * 256 + threadIdx.x;
  int m = i >> 14, e = i & 16383;
  int k = e >> 7, c = e & 127;
  const float* W = (m == 0) ? W1 : (m == 1) ? W2 : Wp;
  wt[m * 16384 + c * 128 + k] = f2bf(W[e]);
}

// ---- bucket counts via per-block LDS histogram ----
__global__ void k_bcount(const int* __restrict__ row, unsigned* __restrict__ cnt){
  __shared__ unsigned hist[NBKT];
  for (int i = threadIdx.x; i < NBKT; i += 512) hist[i] = 0;
  __syncthreads();
  #pragma unroll
  for (int j = 0; j < 4; ++j){
    int i = blockIdx.x * 2048 + j * 512 + threadIdx.x;
    if (i < NE) atomicAdd(&hist[row[i] >> 8], 1u);
  }
  __syncthreads();
  for (int i = threadIdx.x; i < NBKT; i += 512){
    unsigned v = hist[i];
    if (v) atomicAdd(&cnt[i], v);
  }
}

// ---- exclusive scan of NBKT counts (1 block) -> bb, cur ----
__global__ void k_bscan(const unsigned* __restrict__ cnt, unsigned* __restrict__ bb,
                        unsigned* __restrict__ cur){
  __shared__ unsigned wsum[4];
  int t = threadIdx.x, lane = t & 63, w = t >> 6;
  unsigned c4[4], s = 0;
  #pragma unroll
  for (int j = 0; j < 4; ++j){
    int idx = t * 4 + j;
    c4[j] = (idx < NBKT) ? cnt[idx] : 0u;
    s += c4[j];
  }
  unsigned inc = s;
  #pragma unroll
  for (int off = 1; off < 64; off <<= 1){
    unsigned n = __shfl_up(inc, (unsigned)off, 64);
    if (lane >= off) inc += n;
  }
  if (lane == 63) wsum[w] = inc;
  __syncthreads();
  unsigned prior = 0;
  for (int i = 0; i < w; ++i) prior += wsum[i];
  unsigned excl = prior + (inc - s);
  #pragma unroll
  for (int j = 0; j < 4; ++j){
    int idx = t * 4 + j;
    if (idx < NBKT){
      bb[idx] = excl; cur[idx] = excl;
      excl += c4[j];
      if (idx == NBKT - 1) bb[NBKT] = excl;
    }
  }
}

// ---- bin edges into bucket regions (block-batched cursor grabs) ----
__global__ void k_bfill(const int* __restrict__ row, const int* __restrict__ col,
                        unsigned* __restrict__ cur, unsigned* __restrict__ pairs){
  __shared__ unsigned hist[NBKT], base[NBKT];
  for (int i = threadIdx.x; i < NBKT; i += 512) hist[i] = 0;
  __syncthreads();
  int r[16], c[16];
  #pragma unroll
  for (int j = 0; j < 16; ++j){
    int i = blockIdx.x * 8192 + j * 512 + threadIdx.x;
    r[j] = -1;
    if (i < NE){ r[j] = row[i]; c[j] = col[i]; atomicAdd(&hist[r[j] >> 8], 1u); }
  }
  __syncthreads();
  for (int i = threadIdx.x; i < NBKT; i += 512){
    unsigned n = hist[i];
    base[i] = n ? atomicAdd(&cur[i], n) : 0u;
    hist[i] = 0;
  }
  __syncthreads();
  #pragma unroll
  for (int j = 0; j < 16; ++j){
    if (r[j] >= 0){
      int b = r[j] >> 8;
      unsigned pos = base[b] + atomicAdd(&hist[b], 1u);
      pairs[pos] = ((unsigned)(r[j] & 255) << 18) | (unsigned)c[j];
    }
  }
}

// ---- per bucket: counting-sort pairs by local row IN PLACE, emit rowptr ----
__launch_bounds__(256)
__global__ void k_sort(const unsigned* __restrict__ bb,
                       unsigned* __restrict__ pairs,
                       unsigned* __restrict__ rowptr){
  __shared__ unsigned raw[MAXE], srt[MAXE];
  __shared__ unsigned hist[256], start[257], cur[256];
  __shared__ unsigned wsum[4];
  const int b = blockIdx.x, t = threadIdx.x;
  const int lane = t & 63, w = t >> 6;
  const unsigned base0 = bb[b], cnt = bb[b + 1] - base0;
  hist[t] = 0; cur[t] = 0;
  __syncthreads();

  if (cnt <= MAXE){
    for (unsigned i = t; i < cnt; i += 256){
      unsigned p = pairs[base0 + i];
      raw[i] = p;
      atomicAdd(&hist[p >> 18], 1u);
    }
  } else {
    for (unsigned i = t; i < cnt; i += 256)
      atomicAdd(&hist[pairs[base0 + i] >> 18], 1u);
  }
  __syncthreads();
  // exclusive scan hist -> start
  unsigned v = hist[t], inc = v;
  #pragma unroll
  for (int off = 1; off < 64; off <<= 1){
    unsigned n = __shfl_up(inc, (unsigned)off, 64);
    if (lane >= off) inc += n;
  }
  if (lane == 63) wsum[w] = inc;
  __syncthreads();
  unsigned prior = 0;
  for (int i = 0; i < w; ++i) prior += wsum[i];
  start[t] = prior + inc - v;
  if (t == 255) start[256] = prior + inc;
  __syncthreads();

  {
    int idx = b * 256 + t;
    if (idx <= NSP) rowptr[idx] = base0 + start[t];
  }

  if (cnt <= MAXE){
    for (unsigned i = t; i < cnt; i += 256){
      unsigned p = raw[i], lr = p >> 18;
      unsigned slot = start[lr] + atomicAdd(&cur[lr], 1u);
      srt[slot] = p & 0x3FFFFu;
    }
    __syncthreads();
    for (unsigned i = t; i < cnt; i += 256) pairs[base0 + i] = srt[i];
  }
  // overflow buckets (statistically unreachable): left unsorted; gather falls back
}

// ---- one wave per spot: gather ub rows, write normalized bf16 agg ----
__launch_bounds__(256)
__global__ void k_gather(const unsigned short* __restrict__ ub,
                         const unsigned* __restrict__ bb,
                         const unsigned* __restrict__ rowptr,
                         const unsigned* __restrict__ pairs,
                         unsigned short* __restrict__ aggb){
  int wid = (blockIdx.x * 256 + threadIdx.x) >> 6;
  int lane = threadIdx.x & 63;
  if (wid >= NSP) return;
  int b = wid >> 8;
  unsigned bc = bb[b + 1] - bb[b];
  unsigned e0 = rowptr[wid], e1 = rowptr[wid + 1];
  int deg = (int)(e1 - e0);
  float a0 = 0.f, a1 = 0.f;
  if (bc <= MAXE){
    for (int base = 0; base < deg; base += 64){
      int n = deg - base; if (n > 64) n = 64;
      int myidx = (lane < n) ? (int)(pairs[e0 + base + lane] & 0x3FFFFu) : 0;
      for (int j = 0; j < n; j += 8){
        unsigned vv[8]; float m[8];
        #pragma unroll
        for (int q = 0; q < 8; ++q){
          int jj = j + q;
          m[q] = (jj < n) ? 1.f : 0.f;
          if (jj >= n) jj = n - 1;
          int c = __shfl(myidx, jj);
          vv[q] = *(const unsigned*)(ub + (size_t)c * DIM + lane * 2);
        }
        #pragma unroll
        for (int q = 0; q < 8; ++q){
          a0 = fmaf(m[q], bflo(vv[q]), a0);
          a1 = fmaf(m[q], bfhi(vv[q]), a1);
        }
      }
    }
  } else {
    // unsorted overflow bucket: deterministic in-order scan filter
    unsigned p0 = bb[b], p1 = bb[b + 1];
    int lr = wid & 255;
    deg = 0;
    for (unsigned e = p0; e < p1; ++e){
      unsigned p = pairs[e];
      if ((int)(p >> 18) == lr){
        ++deg;
        unsigned vv = *(const unsigned*)(ub + (size_t)(p & 0x3FFFFu) * DIM + lane * 2);
        a0 += bflo(vv); a1 += bfhi(vv);
      }
    }
  }
  float scl = deg ? 1.f / (float)deg : 0.f;
  unsigned o = (unsigned)f2bf(a0 * scl) | ((unsigned)f2bf(a1 * scl) << 16);
  *(unsigned*)(aggb + (size_t)wid * DIM + lane * 2) = o;
}

// ---- fused: out = (leaky(u@W1+b1)@W2 + b2) + leaky(aggn@Wp + bp) ----
__launch_bounds__(1024)
__global__ void k_final(const unsigned short* __restrict__ ub,
                        const float* __restrict__ b1,
                        const float* __restrict__ b2,
                        const float* __restrict__ bp,
                        const unsigned short* __restrict__ wt,
                        const unsigned short* __restrict__ aggb,
                        float* __restrict__ out){
  __shared__ __align__(16) char smem[163840];   // 3x32KB W^T + 16x4KB h

  for (int c = threadIdx.x; c < 6144; c += 1024){
    int m = c >> 11, cc = c & 2047;
    int i = cc >> 4, kb = (cc & 15) << 4;
    short8 v = *(const short8*)(wt + m * 16384 + i * 128 + (kb >> 1));
    *(short8*)(smem + m * 32768 + lbyte(i, kb)) = v;
  }
  __syncthreads();

  const int wid = threadIdx.x >> 6, lane = threadIdx.x & 63;
  const int l15 = lane & 15, kg = lane >> 4;
  char* hbuf = smem + 98304 + wid * 4096;

  int tile = blockIdx.x * 16 + wid;
  if (tile >= NTILE) return;
  int s = tile * 16 + l15;
  const size_t srow = (size_t)s * DIM;

  f32x4 acc[8], hh[8];
  #pragma unroll
  for (int ft = 0; ft < 8; ++ft){ acc[ft] = (f32x4){0.f,0.f,0.f,0.f}; hh[ft] = (f32x4){0.f,0.f,0.f,0.f}; }

  // ---- stage C: acc = Wp^T @ aggn^T ----
  #pragma unroll
  for (int ks = 0; ks < 4; ++ks){
    short8 bf = *(const short8*)(aggb + srow + ks * 32 + kg * 8);
    #pragma unroll
    for (int ft = 0; ft < 8; ++ft){
      short8 af = *(const short8*)(smem + 2 * 32768 + lbyte(ft * 16 + l15, ks * 64 + kg * 16));
      acc[ft] = __builtin_amdgcn_mfma_f32_16x16x32_bf16(af, bf, acc[ft], 0, 0, 0);
    }
  }
  #pragma unroll
  for (int ft = 0; ft < 8; ++ft){
    int f0 = ft * 16 + kg * 4;
    float4 bv = *(const float4*)(bp + f0);
    acc[ft][0] = lrelu(acc[ft][0] + bv.x);
    acc[ft][1] = lrelu(acc[ft][1] + bv.y);
    acc[ft][2] = lrelu(acc[ft][2] + bv.z);
    acc[ft][3] = lrelu(acc[ft][3] + bv.w);
  }

  // ---- stage A: hh = W1^T @ u^T ----
  #pragma unroll
  for (int ks = 0; ks < 4; ++ks){
    short8 bf = *(const short8*)(ub + srow + ks * 32 + kg * 8);
    #pragma unroll
    for (int ft = 0; ft < 8; ++ft){
      short8 af = *(const short8*)(smem + 0 * 32768 + lbyte(ft * 16 + l15, ks * 64 + kg * 16));
      hh[ft] = __builtin_amdgcn_mfma_f32_16x16x32_bf16(af, bf, hh[ft], 0, 0, 0);
    }
  }
  #pragma unroll
  for (int ft = 0; ft < 8; ++ft){
    int f0 = ft * 16 + kg * 4;
    float4 bv = *(const float4*)(b1 + f0);
    short4v hv;
    hv[0] = (short)f2bf(lrelu(hh[ft][0] + bv.x));
    hv[1] = (short)f2bf(lrelu(hh[ft][1] + bv.y));
    hv[2] = (short)f2bf(lrelu(hh[ft][2] + bv.z));
    hv[3] = (short)f2bf(lrelu(hh[ft][3] + bv.w));
    *(short4v*)(hbuf + lbyte(l15, 2 * f0)) = hv;
  }

  // ---- stage B: acc += W2^T @ h^T ----
  #pragma unroll
  for (int ks = 0; ks < 4; ++ks){
    short8 bf = *(const short8*)(hbuf + lbyte(l15, ks * 64 + kg * 16));
    #pragma unroll
    for (int ft = 0; ft < 8; ++ft){
      short8 af = *(const short8*)(smem + 1 * 32768 + lbyte(ft * 16 + l15, ks * 64 + kg * 16));
      acc[ft] = __builtin_amdgcn_mfma_f32_16x16x32_bf16(af, bf, acc[ft], 0, 0, 0);
    }
  }

  // ---- epilogue ----
  #pragma unroll
  for (int ft = 0; ft < 8; ++ft){
    int f0 = ft * 16 + kg * 4;
    float4 bv = *(const float4*)(b2 + f0);
    f32x4 o = acc[ft];
    o[0] += bv.x; o[1] += bv.y; o[2] += bv.z; o[3] += bv.w;
    *(f32x4*)(out + srow + f0) = o;
  }
}

extern "C" void kernel_launch(void* const* d_in, const int* in_sizes, int n_in,
                              void* d_out, int out_size, void* d_ws, size_t ws_size,
                              hipStream_t stream){
  (void)in_sizes; (void)n_in; (void)out_size; (void)ws_size;
  const float* u  = (const float*)d_in[0];
  const float* W1 = (const float*)d_in[1];
  const float* b1 = (const float*)d_in[2];
  const float* W2 = (const float*)d_in[3];
  const float* b2 = (const float*)d_in[4];
  const float* Wp = (const float*)d_in[5];
  const float* bp = (const float*)d_in[6];
  const int* row  = (const int*)d_in[7];
  const int* col  = (const int*)d_in[8];
  char* ws = (char*)d_ws;
  unsigned* bb     = (unsigned*)(ws + OFF_BB);
  unsigned* cur    = (unsigned*)(ws + OFF_CUR);
  unsigned* bcnt   = (unsigned*)(ws + OFF_BCNT);
  unsigned* pairs  = (unsigned*)(ws + OFF_PAIRS);
  unsigned* rowptr = (unsigned*)(ws + OFF_ROWPTR);
  unsigned short* wt    = (unsigned short*)(ws + OFF_WT);
  unsigned short* ubp   = (unsigned short*)(ws + OFF_UB);
  unsigned short* aggbp = (unsigned short*)(ws + OFF_AGGB);
  float* out = (float*)d_out;

  hipMemsetAsync(ws + OFF_BCNT, 0, 3136, stream);
  k_wt    <<<192, 256, 0, stream>>>(W1, W2, Wp, wt);
  k_cast  <<<12500, 256, 0, stream>>>(u, ubp);
  k_bcount<<<586, 512, 0, stream>>>(row, bcnt);
  k_bscan <<<1, 256, 0, stream>>>(bcnt, bb, cur);
  k_bfill <<<147, 512, 0, stream>>>(row, col, cur, pairs);
  k_sort  <<<NBKT, 256, 0, stream>>>(bb, pairs, rowptr);
  k_gather<<<50000, 256, 0, stream>>>(ubp, bb, rowptr, pairs, aggbp);
  k_final <<<782, 1024, 0, stream>>>(ubp, b1, b2, bp, wt, aggbp, out);
}

// Round 5
// 228.498 us; speedup vs baseline: 1.6188x; 1.0031x over previous
//
#include <hip/hip_runtime.h>

#define NSP 200000
#define NE  1200000
#define DIM 128
#define NTILE 12500        // NSP/16
#define NBKT  782          // ceil(NSP/256) row-range buckets
#define MAXE  2560         // per-bucket edge capacity for LDS sort (mean 1536, sigma 39)

typedef __attribute__((ext_vector_type(8))) short short8;
typedef __attribute__((ext_vector_type(4))) short short4v;
typedef __attribute__((ext_vector_type(4))) float f32x4;

// ---- workspace byte offsets (16B aligned), total ~56.9MB ----
#define OFF_BB     0               // (NBKT+1)*4
#define OFF_CUR    3136            // NBKT*4
#define OFF_BCNT   6272            // NBKT*4
#define OFF_PAIRS  9408            // NE*4 packed (lr<<18)|col; sorted in place by k_sort
#define OFF_ROWPTR 4809408         // (NSP+1)*4
#define OFF_WT     5609424         // 3*128*128*2 bf16
#define OFF_UB     5707728         // NSP*128*2 bf16 u   end=56907728

__device__ __forceinline__ unsigned short f2bf(float x){
  union { float f; unsigned u; } v; v.f = x;
  unsigned r = v.u + 0x7FFFu + ((v.u >> 16) & 1u);   // RNE
  return (unsigned short)(r >> 16);
}
__device__ __forceinline__ float bflo(unsigned v){ union{unsigned u;float f;}x; x.u = v << 16; return x.f; }
__device__ __forceinline__ float bfhi(unsigned v){ union{unsigned u;float f;}x; x.u = v & 0xffff0000u; return x.f; }
__device__ __forceinline__ float lrelu(float x){ return x > 0.f ? x : 0.2f * x; }

// swizzled byte offset inside a [rows][128] bf16 LDS tile (row stride 256B)
__device__ __forceinline__ int lbyte(int row, int kb){
  return row * 256 + (kb ^ ((row & 7) << 4));
}

// ---- u (f32) -> ub (bf16) ----
__global__ void k_cast(const float* __restrict__ u, unsigned short* __restrict__ ub){
  size_t i = (size_t)blockIdx.x * 256 + threadIdx.x;
  const float4* p = (const float4*)(u + i * 8);
  float4 x0 = p[0], x1 = p[1];
  short8 v;
  v[0]=(short)f2bf(x0.x); v[1]=(short)f2bf(x0.y); v[2]=(short)f2bf(x0.z); v[3]=(short)f2bf(x0.w);
  v[4]=(short)f2bf(x1.x); v[5]=(short)f2bf(x1.y); v[6]=(short)f2bf(x1.z); v[7]=(short)f2bf(x1.w);
  *(short8*)(ub + i * 8) = v;
}

// ---- transpose W's to bf16 W^T ----
__global__ void k_wt(const float* __restrict__ W1, const float* __restrict__ W2,
                     const float* __restrict__ Wp, unsigned short* __restrict__ wt){
  int i = blockIdx.x * 256 + threadIdx.x;
  int m = i >> 14, e = i & 16383;
  int k = e >> 7, c = e & 127;
  const float* W = (m == 0) ? W1 : (m == 1) ? W2 : Wp;
  wt[m * 16384 + c * 128 + k] = f2bf(W[e]);
}

// ---- bucket counts via per-block LDS histogram ----
__global__ void k_bcount(const int* __restrict__ row, unsigned* __restrict__ cnt){
  __shared__ unsigned hist[NBKT];
  for (int i = threadIdx.x; i < NBKT; i += 512) hist[i] = 0;
  __syncthreads();
  #pragma unroll
  for (int j = 0; j < 4; ++j){
    int i = blockIdx.x * 2048 + j * 512 + threadIdx.x;
    if (i < NE) atomicAdd(&hist[row[i] >> 8], 1u);
  }
  __syncthreads();
  for (int i = threadIdx.x; i < NBKT; i += 512){
    unsigned v = hist[i];
    if (v) atomicAdd(&cnt[i], v);
  }
}

// ---- exclusive scan of NBKT counts (1 block) -> bb, cur ----
__global__ void k_bscan(const unsigned* __restrict__ cnt, unsigned* __restrict__ bb,
                        unsigned* __restrict__ cur){
  __shared__ unsigned wsum[4];
  int t = threadIdx.x, lane = t & 63, w = t >> 6;
  unsigned c4[4], s = 0;
  #pragma unroll
  for (int j = 0; j < 4; ++j){
    int idx = t * 4 + j;
    c4[j] = (idx < NBKT) ? cnt[idx] : 0u;
    s += c4[j];
  }
  unsigned inc = s;
  #pragma unroll
  for (int off = 1; off < 64; off <<= 1){
    unsigned n = __shfl_up(inc, (unsigned)off, 64);
    if (lane >= off) inc += n;
  }
  if (lane == 63) wsum[w] = inc;
  __syncthreads();
  unsigned prior = 0;
  for (int i = 0; i < w; ++i) prior += wsum[i];
  unsigned excl = prior + (inc - s);
  #pragma unroll
  for (int j = 0; j < 4; ++j){
    int idx = t * 4 + j;
    if (idx < NBKT){
      bb[idx] = excl; cur[idx] = excl;
      excl += c4[j];
      if (idx == NBKT - 1) bb[NBKT] = excl;
    }
  }
}

// ---- bin edges into bucket regions (block-batched cursor grabs) ----
__global__ void k_bfill(const int* __restrict__ row, const int* __restrict__ col,
                        unsigned* __restrict__ cur, unsigned* __restrict__ pairs){
  __shared__ unsigned hist[NBKT], base[NBKT];
  for (int i = threadIdx.x; i < NBKT; i += 512) hist[i] = 0;
  __syncthreads();
  int r[16], c[16];
  #pragma unroll
  for (int j = 0; j < 16; ++j){
    int i = blockIdx.x * 8192 + j * 512 + threadIdx.x;
    r[j] = -1;
    if (i < NE){ r[j] = row[i]; c[j] = col[i]; atomicAdd(&hist[r[j] >> 8], 1u); }
  }
  __syncthreads();
  for (int i = threadIdx.x; i < NBKT; i += 512){
    unsigned n = hist[i];
    base[i] = n ? atomicAdd(&cur[i], n) : 0u;
    hist[i] = 0;
  }
  __syncthreads();
  #pragma unroll
  for (int j = 0; j < 16; ++j){
    if (r[j] >= 0){
      int b = r[j] >> 8;
      unsigned pos = base[b] + atomicAdd(&hist[b], 1u);
      pairs[pos] = ((unsigned)(r[j] & 255) << 18) | (unsigned)c[j];
    }
  }
}

// ---- per bucket: counting-sort pairs by local row IN PLACE, emit global CSR rowptr ----
__launch_bounds__(256)
__global__ void k_sort(const unsigned* __restrict__ bb,
                       unsigned* __restrict__ pairs,
                       unsigned* __restrict__ rowptr){
  __shared__ unsigned raw[MAXE], srt[MAXE];
  __shared__ unsigned hist[256], start[257], cur[256];
  __shared__ unsigned wsum[4];
  const int b = blockIdx.x, t = threadIdx.x;
  const int lane = t & 63, w = t >> 6;
  const unsigned base0 = bb[b], cnt = bb[b + 1] - base0;
  hist[t] = 0; cur[t] = 0;
  __syncthreads();

  if (cnt <= MAXE){
    for (unsigned i = t; i < cnt; i += 256){
      unsigned p = pairs[base0 + i];
      raw[i] = p;
      atomicAdd(&hist[p >> 18], 1u);
    }
  } else {
    for (unsigned i = t; i < cnt; i += 256)
      atomicAdd(&hist[pairs[base0 + i] >> 18], 1u);
  }
  __syncthreads();
  // exclusive scan hist -> start
  unsigned v = hist[t], inc = v;
  #pragma unroll
  for (int off = 1; off < 64; off <<= 1){
    unsigned n = __shfl_up(inc, (unsigned)off, 64);
    if (lane >= off) inc += n;
  }
  if (lane == 63) wsum[w] = inc;
  __syncthreads();
  unsigned prior = 0;
  for (int i = 0; i < w; ++i) prior += wsum[i];
  start[t] = prior + inc - v;
  if (t == 255) start[256] = prior + inc;
  __syncthreads();

  {
    int idx = b * 256 + t;
    if (idx <= NSP) rowptr[idx] = base0 + start[t];
  }

  if (cnt <= MAXE){
    for (unsigned i = t; i < cnt; i += 256){
      unsigned p = raw[i], lr = p >> 18;
      unsigned slot = start[lr] + atomicAdd(&cur[lr], 1u);
      srt[slot] = p & 0x3FFFFu;
    }
    __syncthreads();
    for (unsigned i = t; i < cnt; i += 256) pairs[base0 + i] = srt[i];
  }
  // overflow buckets (statistically unreachable): left unsorted; fused kernel falls back
}

// ---- fused: gather + out = (leaky(u@W1+b1)@W2 + b2) + leaky(aggn@Wp + bp) ----
// Per 16-spot tile per wave. Lane (kg,l15) gathers agg[l15][ks*32+kg*8..+7] directly
// from edge rows (4 kg-lanes cover the 256B row), normalization folded into fma.
__launch_bounds__(1024)
__global__ void k_final(const unsigned short* __restrict__ ub,
                        const float* __restrict__ b1,
                        const float* __restrict__ b2,
                        const float* __restrict__ bp,
                        const unsigned* __restrict__ bb,
                        const unsigned* __restrict__ rowptr,
                        const unsigned* __restrict__ pairs,
                        const unsigned short* __restrict__ wt,
                        float* __restrict__ out){
  __shared__ __align__(16) char smem[163840];   // 3x32KB W^T + 16x4KB h

  // stage all three W^T into LDS (issue first; latency hides under gather)
  for (int c = threadIdx.x; c < 6144; c += 1024){
    int m = c >> 11, cc = c & 2047;
    int i = cc >> 4, kb = (cc & 15) << 4;
    short8 v = *(const short8*)(wt + m * 16384 + i * 128 + (kb >> 1));
    *(short8*)(smem + m * 32768 + lbyte(i, kb)) = v;
  }

  const int wid = threadIdx.x >> 6, lane = threadIdx.x & 63;
  const int l15 = lane & 15, kg = lane >> 4;
  char* hbuf = smem + 98304 + wid * 4096;

  int tile = blockIdx.x * 16 + wid;
  const bool valid = (tile < NTILE);
  int s = (valid ? tile : 0) * 16 + l15;
  const size_t srow = (size_t)s * DIM;

  // early: preload stage-A B-frags (ub row of my spot)
  short8 ufr[4];
  #pragma unroll
  for (int ks = 0; ks < 4; ++ks)
    ufr[ks] = *(const short8*)(ub + srow + ks * 32 + kg * 8);

  // ---- gather: a[ks][q] = (1/deg) * sum_edges ub[c][ks*32+kg*8+q] ----
  float a[4][8];
  #pragma unroll
  for (int ks = 0; ks < 4; ++ks)
    #pragma unroll
    for (int q = 0; q < 8; ++q) a[ks][q] = 0.f;

  if (valid){
    int b = s >> 8;
    unsigned e0 = rowptr[s], e1 = rowptr[s + 1];
    unsigned bc = bb[b + 1] - bb[b];
    float scl = (e1 > e0) ? 1.f / (float)(e1 - e0) : 0.f;
    const unsigned short* ubg = ub + (size_t)kg * 8;
    if (bc <= MAXE){
      for (unsigned j = e0; j < e1; j += 4){
        unsigned rem = e1 - j;
        int o1 = rem > 1 ? 1 : 0, o2 = rem > 2 ? 2 : 0, o3 = rem > 3 ? 3 : 0;
        float mB = rem > 1 ? scl : 0.f, mC = rem > 2 ? scl : 0.f, mD = rem > 3 ? scl : 0.f;
        int cA = (int)(pairs[j]      & 0x3FFFFu);
        int cB = (int)(pairs[j + o1] & 0x3FFFFu);
        int cC = (int)(pairs[j + o2] & 0x3FFFFu);
        int cD = (int)(pairs[j + o3] & 0x3FFFFu);
        const unsigned short* rA = ubg + (size_t)cA * DIM;
        const unsigned short* rB = ubg + (size_t)cB * DIM;
        const unsigned short* rC = ubg + (size_t)cC * DIM;
        const unsigned short* rD = ubg + (size_t)cD * DIM;
        #pragma unroll
        for (int ks = 0; ks < 4; ++ks){
          uint4 vA = *(const uint4*)(rA + ks * 32);
          uint4 vB = *(const uint4*)(rB + ks * 32);
          uint4 vC = *(const uint4*)(rC + ks * 32);
          uint4 vD = *(const uint4*)(rD + ks * 32);
          a[ks][0]=fmaf(scl,bflo(vA.x),a[ks][0]); a[ks][1]=fmaf(scl,bfhi(vA.x),a[ks][1]);
          a[ks][2]=fmaf(scl,bflo(vA.y),a[ks][2]); a[ks][3]=fmaf(scl,bfhi(vA.y),a[ks][3]);
          a[ks][4]=fmaf(scl,bflo(vA.z),a[ks][4]); a[ks][5]=fmaf(scl,bfhi(vA.z),a[ks][5]);
          a[ks][6]=fmaf(scl,bflo(vA.w),a[ks][6]); a[ks][7]=fmaf(scl,bfhi(vA.w),a[ks][7]);
          a[ks][0]=fmaf(mB,bflo(vB.x),a[ks][0]);  a[ks][1]=fmaf(mB,bfhi(vB.x),a[ks][1]);
          a[ks][2]=fmaf(mB,bflo(vB.y),a[ks][2]);  a[ks][3]=fmaf(mB,bfhi(vB.y),a[ks][3]);
          a[ks][4]=fmaf(mB,bflo(vB.z),a[ks][4]);  a[ks][5]=fmaf(mB,bfhi(vB.z),a[ks][5]);
          a[ks][6]=fmaf(mB,bflo(vB.w),a[ks][6]);  a[ks][7]=fmaf(mB,bfhi(vB.w),a[ks][7]);
          a[ks][0]=fmaf(mC,bflo(vC.x),a[ks][0]);  a[ks][1]=fmaf(mC,bfhi(vC.x),a[ks][1]);
          a[ks][2]=fmaf(mC,bflo(vC.y),a[ks][2]);  a[ks][3]=fmaf(mC,bfhi(vC.y),a[ks][3]);
          a[ks][4]=fmaf(mC,bflo(vC.z),a[ks][4]);  a[ks][5]=fmaf(mC,bfhi(vC.z),a[ks][5]);
          a[ks][6]=fmaf(mC,bflo(vC.w),a[ks][6]);  a[ks][7]=fmaf(mC,bfhi(vC.w),a[ks][7]);
          a[ks][0]=fmaf(mD,bflo(vD.x),a[ks][0]);  a[ks][1]=fmaf(mD,bfhi(vD.x),a[ks][1]);
          a[ks][2]=fmaf(mD,bflo(vD.y),a[ks][2]);  a[ks][3]=fmaf(mD,bfhi(vD.y),a[ks][3]);
          a[ks][4]=fmaf(mD,bflo(vD.z),a[ks][4]);  a[ks][5]=fmaf(mD,bfhi(vD.z),a[ks][5]);
          a[ks][6]=fmaf(mD,bflo(vD.w),a[ks][6]);  a[ks][7]=fmaf(mD,bfhi(vD.w),a[ks][7]);
        }
      }
    } else {
      // unsorted overflow bucket: deterministic in-order scan filter
      unsigned p0 = bb[b], p1 = bb[b + 1];
      int lr = s & 255;
      for (unsigned e = p0; e < p1; ++e){
        unsigned p = pairs[e];
        if ((int)(p >> 18) == lr){
          const unsigned short* r = ubg + (size_t)(p & 0x3FFFFu) * DIM;
          #pragma unroll
          for (int ks = 0; ks < 4; ++ks){
            uint4 v = *(const uint4*)(r + ks * 32);
            a[ks][0]=fmaf(scl,bflo(v.x),a[ks][0]); a[ks][1]=fmaf(scl,bfhi(v.x),a[ks][1]);
            a[ks][2]=fmaf(scl,bflo(v.y),a[ks][2]); a[ks][3]=fmaf(scl,bfhi(v.y),a[ks][3]);
            a[ks][4]=fmaf(scl,bflo(v.z),a[ks][4]); a[ks][5]=fmaf(scl,bfhi(v.z),a[ks][5]);
            a[ks][6]=fmaf(scl,bflo(v.w),a[ks][6]); a[ks][7]=fmaf(scl,bfhi(v.w),a[ks][7]);
          }
        }
      }
    }
  }

  // cvt gathered agg to bf16 B-frags
  short8 pa[4];
  #pragma unroll
  for (int ks = 0; ks < 4; ++ks){
    pa[ks][0]=(short)f2bf(a[ks][0]); pa[ks][1]=(short)f2bf(a[ks][1]);
    pa[ks][2]=(short)f2bf(a[ks][2]); pa[ks][3]=(short)f2bf(a[ks][3]);
    pa[ks][4]=(short)f2bf(a[ks][4]); pa[ks][5]=(short)f2bf(a[ks][5]);
    pa[ks][6]=(short)f2bf(a[ks][6]); pa[ks][7]=(short)f2bf(a[ks][7]);
  }

  __syncthreads();
  if (!valid) return;

  f32x4 acc[8], hh[8];
  #pragma unroll
  for (int ft = 0; ft < 8; ++ft){ acc[ft] = (f32x4){0.f,0.f,0.f,0.f}; hh[ft] = (f32x4){0.f,0.f,0.f,0.f}; }

  // ---- stage C: acc = Wp^T @ aggn^T ----
  #pragma unroll
  for (int ks = 0; ks < 4; ++ks){
    #pragma unroll
    for (int ft = 0; ft < 8; ++ft){
      short8 af = *(const short8*)(smem + 2 * 32768 + lbyte(ft * 16 + l15, ks * 64 + kg * 16));
      acc[ft] = __builtin_amdgcn_mfma_f32_16x16x32_bf16(af, pa[ks], acc[ft], 0, 0, 0);
    }
  }
  #pragma unroll
  for (int ft = 0; ft < 8; ++ft){
    int f0 = ft * 16 + kg * 4;
    float4 bv = *(const float4*)(bp + f0);
    acc[ft][0] = lrelu(acc[ft][0] + bv.x);
    acc[ft][1] = lrelu(acc[ft][1] + bv.y);
    acc[ft][2] = lrelu(acc[ft][2] + bv.z);
    acc[ft][3] = lrelu(acc[ft][3] + bv.w);
  }

  // ---- stage A: hh = W1^T @ u^T ----
  #pragma unroll
  for (int ks = 0; ks < 4; ++ks){
    #pragma unroll
    for (int ft = 0; ft < 8; ++ft){
      short8 af = *(const short8*)(smem + 0 * 32768 + lbyte(ft * 16 + l15, ks * 64 + kg * 16));
      hh[ft] = __builtin_amdgcn_mfma_f32_16x16x32_bf16(af, ufr[ks], hh[ft], 0, 0, 0);
    }
  }
  #pragma unroll
  for (int ft = 0; ft < 8; ++ft){
    int f0 = ft * 16 + kg * 4;
    float4 bv = *(const float4*)(b1 + f0);
    short4v hv;
    hv[0] = (short)f2bf(lrelu(hh[ft][0] + bv.x));
    hv[1] = (short)f2bf(lrelu(hh[ft][1] + bv.y));
    hv[2] = (short)f2bf(lrelu(hh[ft][2] + bv.z));
    hv[3] = (short)f2bf(lrelu(hh[ft][3] + bv.w));
    *(short4v*)(hbuf + lbyte(l15, 2 * f0)) = hv;
  }

  // ---- stage B: acc += W2^T @ h^T ----
  #pragma unroll
  for (int ks = 0; ks < 4; ++ks){
    short8 bf = *(const short8*)(hbuf + lbyte(l15, ks * 64 + kg * 16));
    #pragma unroll
    for (int ft = 0; ft < 8; ++ft){
      short8 af = *(const short8*)(smem + 1 * 32768 + lbyte(ft * 16 + l15, ks * 64 + kg * 16));
      acc[ft] = __builtin_amdgcn_mfma_f32_16x16x32_bf16(af, bf, acc[ft], 0, 0, 0);
    }
  }

  // ---- epilogue ----
  #pragma unroll
  for (int ft = 0; ft < 8; ++ft){
    int f0 = ft * 16 + kg * 4;
    float4 bv = *(const float4*)(b2 + f0);
    f32x4 o = acc[ft];
    o[0] += bv.x; o[1] += bv.y; o[2] += bv.z; o[3] += bv.w;
    *(f32x4*)(out + srow + f0) = o;
  }
}

extern "C" void kernel_launch(void* const* d_in, const int* in_sizes, int n_in,
                              void* d_out, int out_size, void* d_ws, size_t ws_size,
                              hipStream_t stream){
  (void)in_sizes; (void)n_in; (void)out_size; (void)ws_size;
  const float* u  = (const float*)d_in[0];
  const float* W1 = (const float*)d_in[1];
  const float* b1 = (const float*)d_in[2];
  const float* W2 = (const float*)d_in[3];
  const float* b2 = (const float*)d_in[4];
  const float* Wp = (const float*)d_in[5];
  const float* bp = (const float*)d_in[6];
  const int* row  = (const int*)d_in[7];
  const int* col  = (const int*)d_in[8];
  char* ws = (char*)d_ws;
  unsigned* bb     = (unsigned*)(ws + OFF_BB);
  unsigned* cur    = (unsigned*)(ws + OFF_CUR);
  unsigned* bcnt   = (unsigned*)(ws + OFF_BCNT);
  unsigned* pairs  = (unsigned*)(ws + OFF_PAIRS);
  unsigned* rowptr = (unsigned*)(ws + OFF_ROWPTR);
  unsigned short* wt  = (unsigned short*)(ws + OFF_WT);
  unsigned short* ubp = (unsigned short*)(ws + OFF_UB);
  float* out = (float*)d_out;

  hipMemsetAsync(ws + OFF_BCNT, 0, 3136, stream);
  k_wt    <<<192, 256, 0, stream>>>(W1, W2, Wp, wt);
  k_cast  <<<12500, 256, 0, stream>>>(u, ubp);
  k_bcount<<<586, 512, 0, stream>>>(row, bcnt);
  k_bscan <<<1, 256, 0, stream>>>(bcnt, bb, cur);
  k_bfill <<<147, 512, 0, stream>>>(row, col, cur, pairs);
  k_sort  <<<NBKT, 256, 0, stream>>>(bb, pairs, rowptr);
  k_final <<<782, 1024, 0, stream>>>(ubp, b1, b2, bp, bb, rowptr, pairs, wt, out);
}